// Round 1
// baseline (2032.579 us; speedup 1.0000x reference)
//
#include <hip/hip_runtime.h>
#include <math.h>

// Problem constants (from reference)
namespace {
constexpr int Bn = 4, Tn = 2048, Cn = 1024, Hn = 16, Dn = 64, INNERn = 1024, OUTn = 1024;
constexpr int Mn = Bn * Tn;            // 8192 tokens
constexpr size_t HEAD_ELEMS = (size_t)Tn * Dn;   // per (b,h) slice
}

// ---------------------------------------------------------------------------
// GEMM: C = scale * A(M x K) * Bw(N x K)^T      (both operands row-contiguous
// along K — dot of rows). 64x64 tile, BK=32, 256 threads, 4x4 micro-tile.
// LDS in [k][m] layout (stride 68 floats => 16B-aligned float4 rows) so the
// inner loop is 2x ds_read_b128 + 16 FMA per k.
// SCATTER=1: write into [B,H,T,D] layout (QKV head split). SCATTER=0: plain.
// ---------------------------------------------------------------------------
template<int SCATTER>
__global__ __launch_bounds__(256)
void gemm_bt(const float* __restrict__ A, const float* __restrict__ Bw,
             float* __restrict__ Cout, int K, int N, float scale)
{
    __shared__ float As[32][68];
    __shared__ float Bs[32][68];
    const int tid = threadIdx.x;
    const int tx = tid & 15, ty = tid >> 4;
    const int n0 = blockIdx.x * 64;
    const int m0 = blockIdx.y * 64;

    float acc[4][4];
#pragma unroll
    for (int i = 0; i < 4; ++i)
#pragma unroll
        for (int j = 0; j < 4; ++j) acc[i][j] = 0.f;

    for (int k0 = 0; k0 < K; k0 += 32) {
#pragma unroll
        for (int it = 0; it < 2; ++it) {
            const int e   = tid + it * 256;   // float4 id within 64x32 tile
            const int row = e >> 3;           // 0..63
            const int kq  = (e & 7) << 2;     // 0,4,...,28
            const float4 a4 = *(const float4*)(A + (size_t)(m0 + row) * K + k0 + kq);
            As[kq + 0][row] = a4.x; As[kq + 1][row] = a4.y;
            As[kq + 2][row] = a4.z; As[kq + 3][row] = a4.w;
            const float4 b4 = *(const float4*)(Bw + (size_t)(n0 + row) * K + k0 + kq);
            Bs[kq + 0][row] = b4.x; Bs[kq + 1][row] = b4.y;
            Bs[kq + 2][row] = b4.z; Bs[kq + 3][row] = b4.w;
        }
        __syncthreads();
#pragma unroll 8
        for (int k = 0; k < 32; ++k) {
            const float4 av = *(const float4*)(&As[k][ty << 2]);
            const float4 bv = *(const float4*)(&Bs[k][tx << 2]);
            const float a_[4] = {av.x, av.y, av.z, av.w};
            const float b_[4] = {bv.x, bv.y, bv.z, bv.w};
#pragma unroll
            for (int i = 0; i < 4; ++i)
#pragma unroll
                for (int j = 0; j < 4; ++j)
                    acc[i][j] = fmaf(a_[i], b_[j], acc[i][j]);
        }
        __syncthreads();
    }

    if (SCATTER) {
#pragma unroll
        for (int i = 0; i < 4; ++i) {
            const int m = m0 + (ty << 2) + i;
            const int b = m >> 11;            // /T (2048)
            const int t = m & (Tn - 1);
#pragma unroll
            for (int j = 0; j < 4; ++j) {
                const int ig = n0 + (tx << 2) + j;
                const int h = ig >> 6, d = ig & 63;
                Cout[(((size_t)(b * Hn + h)) * Tn + t) * Dn + d] = acc[i][j] * scale;
            }
        }
    } else {
#pragma unroll
        for (int i = 0; i < 4; ++i) {
            const int m = m0 + (ty << 2) + i;
            float4 o4;
            o4.x = acc[i][0] * scale; o4.y = acc[i][1] * scale;
            o4.z = acc[i][2] * scale; o4.w = acc[i][3] * scale;
            *(float4*)(Cout + (size_t)m * N + n0 + (tx << 2)) = o4;
        }
    }
}

// ---------------------------------------------------------------------------
// Flash-style attention. One block per (b,h, 64-row q-tile). 256 threads as
// 16x16; thread owns a 4x4 micro-tile of the 64x64 S / O tiles. Rows of S
// live entirely inside a 16-lane shuffle group (tid = ty*16+tx). K-tile LDS
// buffer is reused to hold P (j-major) between S and PV phases.
// Q is pre-scaled by d^-0.5 = 1/8 at load. Output written in [B,T,H*D].
// ---------------------------------------------------------------------------
__global__ __launch_bounds__(256)
void attn_fwd(const float* __restrict__ Qb, const float* __restrict__ Kb,
              const float* __restrict__ Vb, float* __restrict__ Ob)
{
    __shared__ float Qs[64][68];   // [d][r], pre-scaled
    __shared__ float Ks[64][68];   // [d][c] in S phase; [j][r] (=P) in PV phase
    __shared__ float Vs[64][68];   // [j][c]
    const int tid = threadIdx.x;
    const int tx = tid & 15, ty = tid >> 4;
    const int q0 = blockIdx.x * 64;
    const int bh = blockIdx.y;     // b*16 + h
    const float* Q = Qb + (size_t)bh * HEAD_ELEMS;
    const float* K = Kb + (size_t)bh * HEAD_ELEMS;
    const float* V = Vb + (size_t)bh * HEAD_ELEMS;

#pragma unroll
    for (int it = 0; it < 4; ++it) {
        const int e  = tid + it * 256;   // float4 id within 64x64 tile
        const int r  = e >> 4;
        const int d4 = (e & 15) << 2;
        const float4 v4 = *(const float4*)(Q + (size_t)(q0 + r) * Dn + d4);
        Qs[d4 + 0][r] = v4.x * 0.125f;
        Qs[d4 + 1][r] = v4.y * 0.125f;
        Qs[d4 + 2][r] = v4.z * 0.125f;
        Qs[d4 + 3][r] = v4.w * 0.125f;
    }

    float m_i[4], l_i[4], Oa[4][4];
#pragma unroll
    for (int i = 0; i < 4; ++i) {
        m_i[i] = -INFINITY; l_i[i] = 0.f;
#pragma unroll
        for (int j = 0; j < 4; ++j) Oa[i][j] = 0.f;
    }

    for (int kt = 0; kt < Tn / 64; ++kt) {
        __syncthreads();   // protects Ks/Vs reuse across iterations (and Qs, iter 0)
#pragma unroll
        for (int it = 0; it < 4; ++it) {
            const int e  = tid + it * 256;
            const int r  = e >> 4;
            const int d4 = (e & 15) << 2;
            const float4 kv = *(const float4*)(K + (size_t)(kt * 64 + r) * Dn + d4);
            Ks[d4 + 0][r] = kv.x; Ks[d4 + 1][r] = kv.y;
            Ks[d4 + 2][r] = kv.z; Ks[d4 + 3][r] = kv.w;
            const float4 vv = *(const float4*)(V + (size_t)(kt * 64 + r) * Dn + d4);
            *(float4*)(&Vs[r][d4]) = vv;
        }
        __syncthreads();

        // ---- S = (Q/8) K^T, 4x4 per thread ----
        float s[4][4];
#pragma unroll
        for (int i = 0; i < 4; ++i)
#pragma unroll
            for (int j = 0; j < 4; ++j) s[i][j] = 0.f;
#pragma unroll 8
        for (int d = 0; d < 64; ++d) {
            const float4 qa = *(const float4*)(&Qs[d][ty << 2]);
            const float4 ka = *(const float4*)(&Ks[d][tx << 2]);
            const float a_[4] = {qa.x, qa.y, qa.z, qa.w};
            const float b_[4] = {ka.x, ka.y, ka.z, ka.w};
#pragma unroll
            for (int i = 0; i < 4; ++i)
#pragma unroll
                for (int j = 0; j < 4; ++j)
                    s[i][j] = fmaf(a_[i], b_[j], s[i][j]);
        }

        // ---- online softmax (rows inside 16-lane groups) ----
#pragma unroll
        for (int i = 0; i < 4; ++i) {
            float mx = fmaxf(fmaxf(s[i][0], s[i][1]), fmaxf(s[i][2], s[i][3]));
            mx = fmaxf(mx, __shfl_xor(mx, 1, 16));
            mx = fmaxf(mx, __shfl_xor(mx, 2, 16));
            mx = fmaxf(mx, __shfl_xor(mx, 4, 16));
            mx = fmaxf(mx, __shfl_xor(mx, 8, 16));
            const float mnew = fmaxf(m_i[i], mx);
            const float alpha = __expf(m_i[i] - mnew);   // 0 on first tile
            m_i[i] = mnew;
            float rs = 0.f;
#pragma unroll
            for (int j = 0; j < 4; ++j) { s[i][j] = __expf(s[i][j] - mnew); rs += s[i][j]; }
            rs += __shfl_xor(rs, 1, 16);
            rs += __shfl_xor(rs, 2, 16);
            rs += __shfl_xor(rs, 4, 16);
            rs += __shfl_xor(rs, 8, 16);
            l_i[i] = l_i[i] * alpha + rs;
#pragma unroll
            for (int j = 0; j < 4; ++j) Oa[i][j] *= alpha;
        }

        __syncthreads();          // everyone done reading Ks as K
        // ---- stash P into Ks buffer, layout [j][r] ----
#pragma unroll
        for (int i = 0; i < 4; ++i)
#pragma unroll
            for (int j = 0; j < 4; ++j)
                Ks[(tx << 2) + j][(ty << 2) + i] = s[i][j];
        __syncthreads();

        // ---- O += P V ----
#pragma unroll 8
        for (int j = 0; j < 64; ++j) {
            const float4 pv = *(const float4*)(&Ks[j][ty << 2]);
            const float4 vv = *(const float4*)(&Vs[j][tx << 2]);
            const float p_[4] = {pv.x, pv.y, pv.z, pv.w};
            const float v_[4] = {vv.x, vv.y, vv.z, vv.w};
#pragma unroll
            for (int i = 0; i < 4; ++i)
#pragma unroll
                for (int jj = 0; jj < 4; ++jj)
                    Oa[i][jj] = fmaf(p_[i], v_[jj], Oa[i][jj]);
        }
    }

    // ---- epilogue: normalize and write [B,T,H*D] ----
    const int b = bh >> 4, h = bh & 15;
#pragma unroll
    for (int i = 0; i < 4; ++i) {
        const float inv = 1.0f / l_i[i];
        const int t = q0 + (ty << 2) + i;
        float4 o4;
        o4.x = Oa[i][0] * inv; o4.y = Oa[i][1] * inv;
        o4.z = Oa[i][2] * inv; o4.w = Oa[i][3] * inv;
        *(float4*)(Ob + ((size_t)(b * Tn + t)) * INNERn + h * Dn + (tx << 2)) = o4;
    }
}

// ---------------------------------------------------------------------------
extern "C" void kernel_launch(void* const* d_in, const int* in_sizes, int n_in,
                              void* d_out, int out_size, void* d_ws, size_t ws_size,
                              hipStream_t stream)
{
    const float* x  = (const float*)d_in[0];
    const float* Wk = (const float*)d_in[1];
    const float* Wq = (const float*)d_in[2];
    const float* Wv = (const float*)d_in[3];
    const float* Wp = (const float*)d_in[4];
    float* out = (float*)d_out;

    // ws layout (floats): q | k | v | attn_out, each Mn*INNERn = 8388608
    float* ws = (float*)d_ws;
    const size_t SEG = (size_t)Mn * INNERn;
    float* q  = ws;
    float* k  = ws + SEG;
    float* v  = ws + 2 * SEG;
    float* ao = ws + 3 * SEG;

    const float scale_in = 1.0f / 32.0f;   // C^-0.5
    const float scale_p  = 1.0f / 32.0f;   // INNER^-0.5

    const dim3 blk(256);
    const dim3 gproj(INNERn / 64, Mn / 64);          // 16 x 128

    gemm_bt<1><<<gproj, blk, 0, stream>>>(x, Wq, q, Cn, INNERn, scale_in);
    gemm_bt<1><<<gproj, blk, 0, stream>>>(x, Wk, k, Cn, INNERn, scale_in);
    gemm_bt<1><<<gproj, blk, 0, stream>>>(x, Wv, v, Cn, INNERn, scale_in);

    attn_fwd<<<dim3(Tn / 64, Bn * Hn), blk, 0, stream>>>(q, k, v, ao);

    gemm_bt<0><<<dim3(OUTn / 64, Mn / 64), blk, 0, stream>>>(ao, Wp, out, INNERn, OUTn, scale_p);
}

// Round 2
// 461.702 us; speedup vs baseline: 4.4024x; 4.4024x over previous
//
#include <hip/hip_runtime.h>
#include <math.h>

typedef __attribute__((ext_vector_type(8))) short bh8;    // 8 bf16 in 4 VGPRs
typedef __attribute__((ext_vector_type(4))) float f32x4;  // MFMA accumulator

namespace {
constexpr int Bn = 4, Tn = 2048, Cn = 1024, Hn = 16, Dn = 64, INNERn = 1024, OUTn = 1024;
constexpr int Mn = Bn * Tn;  // 8192 tokens
}

// async 16B global->LDS (wave-uniform base + lane*16 placement)
__device__ __forceinline__ void glds16(const void* g, void* l) {
    __builtin_amdgcn_global_load_lds(
        (const __attribute__((address_space(1))) void*)g,
        (__attribute__((address_space(3))) void*)l, 16, 0, 0);
}

// fp32 -> bf16 round-to-nearest-even (inputs are well-behaved, no NaN care)
__device__ __forceinline__ ushort f2bf(float f) {
    union { float f; unsigned u; } v; v.f = f;
    unsigned r = v.u + 0x7fffu + ((v.u >> 16) & 1u);
    return (ushort)(r >> 16);
}

__global__ __launch_bounds__(256)
void cvt_bf16(const float* __restrict__ s, ushort* __restrict__ d, int n4, float scale) {
    int i = blockIdx.x * 256 + threadIdx.x;
    if (i >= n4) return;
    float4 f = ((const float4*)s)[i];
    ushort4 o;
    o.x = f2bf(f.x * scale); o.y = f2bf(f.y * scale);
    o.z = f2bf(f.z * scale); o.w = f2bf(f.w * scale);
    ((ushort4*)d)[i] = o;
}

// ---------------------------------------------------------------------------
// bf16 MFMA GEMM: C = scale * A(MxK) * Bw(NxK)^T. 128x128 tile, BK=32,
// 256 thr = 4 waves (2x2), each wave 4x4 grid of 16x16x32 MFMAs.
// LDS tiles stored [m][k] rows of 64B; staged via global_load_lds width 16.
// SCATTER=1: bf16 out into [B,H,T,D]. SCATTER=0: fp32 out row-major MxN.
// ---------------------------------------------------------------------------
template<int SCATTER>
__global__ __launch_bounds__(256)
void gemm_bf16(const ushort* __restrict__ A, const ushort* __restrict__ Bw,
               void* __restrict__ Cout, int K, int N, float scale)
{
    __shared__ char As[8192];   // addr(m,k) = m*64 + k*2
    __shared__ char Bs[8192];
    const int tid = threadIdx.x;
    const int w = tid >> 6, lane = tid & 63, quad = lane >> 4, l = lane & 15;
    const int n0 = blockIdx.x * 128, m0 = blockIdx.y * 128;
    const int wm = w >> 1, wn = w & 1;

    f32x4 acc[4][4];
#pragma unroll
    for (int i = 0; i < 4; ++i)
#pragma unroll
        for (int j = 0; j < 4; ++j) acc[i][j] = (f32x4){0.f, 0.f, 0.f, 0.f};

    for (int k0 = 0; k0 < K; k0 += 32) {
        __syncthreads();
#pragma unroll
        for (int rr = 0; rr < 2; ++rr) {
            const int rho = w * 2 + rr;
            const int row = rho * 16 + (lane >> 2);
            const int kq  = (lane & 3) * 8;
            glds16(A  + (size_t)(m0 + row) * K + k0 + kq, As + rho * 1024 + lane * 16);
            glds16(Bw + (size_t)(n0 + row) * K + k0 + kq, Bs + rho * 1024 + lane * 16);
        }
        __syncthreads();
        bh8 af[4], bf[4];
#pragma unroll
        for (int mf = 0; mf < 4; ++mf)
            af[mf] = *(const bh8*)(As + (wm * 64 + mf * 16 + l) * 64 + quad * 16);
#pragma unroll
        for (int nf = 0; nf < 4; ++nf)
            bf[nf] = *(const bh8*)(Bs + (wn * 64 + nf * 16 + l) * 64 + quad * 16);
#pragma unroll
        for (int mf = 0; mf < 4; ++mf)
#pragma unroll
            for (int nf = 0; nf < 4; ++nf)
                acc[mf][nf] = __builtin_amdgcn_mfma_f32_16x16x32_bf16(af[mf], bf[nf], acc[mf][nf], 0, 0, 0);
    }

    // epilogue: C/D layout col = l, row = quad*4 + reg
    if (SCATTER) {
        ushort* dU = (ushort*)Cout;
#pragma unroll
        for (int mf = 0; mf < 4; ++mf)
#pragma unroll
            for (int nf = 0; nf < 4; ++nf) {
                const int mb = m0 + wm * 64 + mf * 16 + quad * 4;
                const int n  = n0 + wn * 64 + nf * 16 + l;
                const int h = n >> 6, dd = n & 63;
#pragma unroll
                for (int reg = 0; reg < 4; ++reg) {
                    const int m = mb + reg;
                    const int b = m >> 11, t = m & (Tn - 1);
                    dU[((size_t)(b * Hn + h) * Tn + t) * Dn + dd] = f2bf(acc[mf][nf][reg] * scale);
                }
            }
    } else {
        float* dF = (float*)Cout;
#pragma unroll
        for (int mf = 0; mf < 4; ++mf)
#pragma unroll
            for (int nf = 0; nf < 4; ++nf) {
                const int mb = m0 + wm * 64 + mf * 16 + quad * 4;
                const int n  = n0 + wn * 64 + nf * 16 + l;
#pragma unroll
                for (int reg = 0; reg < 4; ++reg)
                    dF[(size_t)(mb + reg) * N + n] = acc[mf][nf][reg] * scale;
            }
    }
}

// ---------------------------------------------------------------------------
// MFMA flash attention. Block = (b,h, 64 q-rows), 256 thr = 4 waves; wave w
// owns q-rows w*16..w*16+15. Q/K tiles: LDS layout [d>>5][r][32d] (b128 frag
// reads, global_load_lds staged). V: register-transposed into XOR-swizzled
// chunk layout Vt (c-contiguous runs at fixed d). P: per-wave swizzled LDS
// round-trip (C-layout -> A-layout). Softmax in exp2 domain (log2e folded
// into q upstream). Output bf16 [B,T,H*D].
// ---------------------------------------------------------------------------
__global__ __launch_bounds__(256)
void attn_mfma(const ushort* __restrict__ Qg, const ushort* __restrict__ Kg,
               const ushort* __restrict__ Vg, ushort* __restrict__ Og)
{
    __shared__ char Qs[8192];   // (r,d): (d>>5)*4096 + r*64 + (d&31)*2
    __shared__ char Ks[8192];   // same layout, r = kv row within tile
    __shared__ char Vt[8192];   // (c,d): (c>>5)*4096 + d*64 + ((((c>>3)&3)^(d&3)^((d>>3)&3)))*16 + (c&7)*2
    __shared__ char Ps[8192];   // per-wave 2KB: (r,c): w*2048 + r*128 + (((c>>3)^(r&7))&7)*16 + (c&7)*2

    const int tid = threadIdx.x;
    const int w = tid >> 6, lane = tid & 63, quad = lane >> 4, l = lane & 15;
    const int q0 = blockIdx.x * 64;
    const int bh = blockIdx.y;
    const ushort* Qp = Qg + (size_t)bh * Tn * Dn;
    const ushort* Kp = Kg + (size_t)bh * Tn * Dn;
    const ushort* Vp = Vg + (size_t)bh * Tn * Dn;

    // ---- stage Q tile (once) ----
#pragma unroll
    for (int rr = 0; rr < 2; ++rr) {
        const int rho = w * 2 + rr;                       // 0..7
        const int r = (rho & 3) * 16 + (lane >> 2);
        const int dq = (rho >> 2) * 32 + (lane & 3) * 8;
        glds16(Qp + (size_t)(q0 + r) * Dn + dq, Qs + rho * 1024 + lane * 16);
    }
    __syncthreads();
    bh8 qf[2];
#pragma unroll
    for (int ks = 0; ks < 2; ++ks)
        qf[ks] = *(const bh8*)(Qs + ks * 4096 + (w * 16 + l) * 64 + quad * 16);

    f32x4 o_acc[4];
    float m_i[4], l_i[4];
#pragma unroll
    for (int i = 0; i < 4; ++i) {
        o_acc[i] = (f32x4){0.f, 0.f, 0.f, 0.f};
        m_i[i] = -1e30f; l_i[i] = 0.f;
    }

    for (int kt = 0; kt < Tn / 64; ++kt) {
        __syncthreads();   // previous iter's frag reads done before restage
        // ---- stage K tile ----
#pragma unroll
        for (int rr = 0; rr < 2; ++rr) {
            const int rho = w * 2 + rr;
            const int r = (rho & 3) * 16 + (lane >> 2);
            const int dq = (rho >> 2) * 32 + (lane & 3) * 8;
            glds16(Kp + (size_t)(kt * 64 + r) * Dn + dq, Ks + rho * 1024 + lane * 16);
        }
        // ---- stage V tile, transposed+swizzled ----
#pragma unroll
        for (int rr = 0; rr < 2; ++rr) {
            const int c = w * 16 + rr * 8 + (lane >> 3);
            const int d0 = (lane & 7) * 8;
            ushort tmp[8];
            *(int4*)tmp = *(const int4*)(Vp + (size_t)(kt * 64 + c) * Dn + d0);
            const int cH = c >> 5, cx = (c >> 3) & 3, c7 = c & 7;
#pragma unroll
            for (int j = 0; j < 8; ++j) {
                const int d = d0 + j;
                const int ch = (cx ^ (d & 3) ^ ((d >> 3) & 3)) & 3;
                *(ushort*)(Vt + cH * 4096 + d * 64 + ch * 16 + c7 * 2) = tmp[j];
            }
        }
        __syncthreads();

        // ---- S = Q K^T (rows = quad*4+reg, cols = nt*16+l) ----
        f32x4 s[4];
#pragma unroll
        for (int nt = 0; nt < 4; ++nt) s[nt] = (f32x4){0.f, 0.f, 0.f, 0.f};
#pragma unroll
        for (int ks = 0; ks < 2; ++ks) {
#pragma unroll
            for (int nt = 0; nt < 4; ++nt) {
                bh8 kf = *(const bh8*)(Ks + ks * 4096 + (nt * 16 + l) * 64 + quad * 16);
                s[nt] = __builtin_amdgcn_mfma_f32_16x16x32_bf16(qf[ks], kf, s[nt], 0, 0, 0);
            }
        }

        // ---- online softmax (exp2 domain; rows live in 16-lane groups) ----
#pragma unroll
        for (int reg = 0; reg < 4; ++reg) {
            float mx = fmaxf(fmaxf(s[0][reg], s[1][reg]), fmaxf(s[2][reg], s[3][reg]));
            mx = fmaxf(mx, __shfl_xor(mx, 1, 16));
            mx = fmaxf(mx, __shfl_xor(mx, 2, 16));
            mx = fmaxf(mx, __shfl_xor(mx, 4, 16));
            mx = fmaxf(mx, __shfl_xor(mx, 8, 16));
            const float mn = fmaxf(m_i[reg], mx);
            const float al = __builtin_amdgcn_exp2f(m_i[reg] - mn);
            m_i[reg] = mn;
            float rs = 0.f;
#pragma unroll
            for (int nt = 0; nt < 4; ++nt) {
                s[nt][reg] = __builtin_amdgcn_exp2f(s[nt][reg] - mn);
                rs += s[nt][reg];
            }
            rs += __shfl_xor(rs, 1, 16);
            rs += __shfl_xor(rs, 2, 16);
            rs += __shfl_xor(rs, 4, 16);
            rs += __shfl_xor(rs, 8, 16);
            l_i[reg] = l_i[reg] * al + rs;
#pragma unroll
            for (int dt = 0; dt < 4; ++dt) o_acc[dt][reg] *= al;
        }

        // ---- P (C-layout) -> Ps (A-layout source), per-wave region ----
#pragma unroll
        for (int nt = 0; nt < 4; ++nt)
#pragma unroll
            for (int reg = 0; reg < 4; ++reg) {
                const int r = quad * 4 + reg, c = nt * 16 + l;
                const int x = ((c >> 3) ^ (r & 7)) & 7;
                *(ushort*)(Ps + w * 2048 + r * 128 + x * 16 + (c & 7) * 2) = f2bf(s[nt][reg]);
            }
        __builtin_amdgcn_s_waitcnt(0xC07F);  // lgkmcnt(0): drain our ds_writes (wave-private buffer)

        // ---- O += P V ----
#pragma unroll
        for (int cs = 0; cs < 2; ++cs) {
            const int x = ((cs * 4 + quad) ^ (l & 7)) & 7;
            bh8 pf = *(const bh8*)(Ps + w * 2048 + l * 128 + x * 16);
#pragma unroll
            for (int dt = 0; dt < 4; ++dt) {
                const int d = dt * 16 + l;
                const int ch = (quad ^ (d & 3) ^ ((d >> 3) & 3)) & 3;
                bh8 vf = *(const bh8*)(Vt + cs * 4096 + d * 64 + ch * 16);
                o_acc[dt] = __builtin_amdgcn_mfma_f32_16x16x32_bf16(pf, vf, o_acc[dt], 0, 0, 0);
            }
        }
    }

    // ---- epilogue: normalize, write bf16 [B,T,H*D] ----
    const int b = bh >> 4, h = bh & 15;
#pragma unroll
    for (int reg = 0; reg < 4; ++reg) {
        const float inv = 1.0f / l_i[reg];
        const int t = q0 + w * 16 + quad * 4 + reg;
#pragma unroll
        for (int dt = 0; dt < 4; ++dt)
            Og[((size_t)(b * Tn + t)) * INNERn + h * Dn + dt * 16 + l] = f2bf(o_acc[dt][reg] * inv);
    }
}

// ---------------------------------------------------------------------------
extern "C" void kernel_launch(void* const* d_in, const int* in_sizes, int n_in,
                              void* d_out, int out_size, void* d_ws, size_t ws_size,
                              hipStream_t stream)
{
    const float* x  = (const float*)d_in[0];
    const float* Wk = (const float*)d_in[1];
    const float* Wq = (const float*)d_in[2];
    const float* Wv = (const float*)d_in[3];
    const float* Wp = (const float*)d_in[4];
    float* out = (float*)d_out;

    // workspace (all bf16): x | Wk | Wq | Wv | Wp | q | k | v | ao
    ushort* xb  = (ushort*)d_ws;
    ushort* wkb = xb  + (size_t)Mn * Cn;
    ushort* wqb = wkb + (size_t)INNERn * Cn;
    ushort* wvb = wqb + (size_t)INNERn * Cn;
    ushort* wpb = wvb + (size_t)INNERn * Cn;
    ushort* qw  = wpb + (size_t)OUTn * INNERn;
    ushort* kw  = qw  + (size_t)Mn * INNERn;
    ushort* vw  = kw  + (size_t)Mn * INNERn;
    ushort* aow = vw  + (size_t)Mn * INNERn;

    const dim3 blk(256);
    const int nx4 = Mn * Cn / 4, nw4 = INNERn * Cn / 4;
    // fold C^-0.5 (=1/32, exact) into x; fold INNER^-0.5 into Wp
    cvt_bf16<<<dim3((nx4 + 255) / 256), blk, 0, stream>>>(x,  xb,  nx4, 0.03125f);
    cvt_bf16<<<dim3((nw4 + 255) / 256), blk, 0, stream>>>(Wk, wkb, nw4, 1.0f);
    cvt_bf16<<<dim3((nw4 + 255) / 256), blk, 0, stream>>>(Wq, wqb, nw4, 1.0f);
    cvt_bf16<<<dim3((nw4 + 255) / 256), blk, 0, stream>>>(Wv, wvb, nw4, 1.0f);
    cvt_bf16<<<dim3((nw4 + 255) / 256), blk, 0, stream>>>(Wp, wpb, nw4, 0.03125f);

    const dim3 gproj(INNERn / 128, Mn / 128);   // 8 x 64
    // q folds d^-0.5 * log2(e) so softmax runs in exp2 domain
    gemm_bf16<1><<<gproj, blk, 0, stream>>>(xb, wqb, qw, Cn, INNERn, 0.125f * 1.44269504f);
    gemm_bf16<1><<<gproj, blk, 0, stream>>>(xb, wkb, kw, Cn, INNERn, 1.0f);
    gemm_bf16<1><<<gproj, blk, 0, stream>>>(xb, wvb, vw, Cn, INNERn, 1.0f);

    attn_mfma<<<dim3(Tn / 64, Bn * Hn), blk, 0, stream>>>(qw, kw, vw, aow);

    gemm_bf16<0><<<dim3(OUTn / 128, Mn / 128), blk, 0, stream>>>(aow, wpb, out, INNERn, OUTn, 1.0f);
}

// Round 3
// 407.400 us; speedup vs baseline: 4.9892x; 1.1333x over previous
//
#include <hip/hip_runtime.h>
#include <math.h>

typedef __attribute__((ext_vector_type(8))) short bh8;    // 8 bf16 in 4 VGPRs
typedef __attribute__((ext_vector_type(4))) float f32x4;  // MFMA accumulator

namespace {
constexpr int Bn = 4, Tn = 2048, Cn = 1024, Hn = 16, Dn = 64, INNERn = 1024, OUTn = 1024;
constexpr int Mn = Bn * Tn;  // 8192 tokens
}

// async 16B global->LDS (wave-uniform base + lane*16 placement)
__device__ __forceinline__ void glds16(const void* g, void* l) {
    __builtin_amdgcn_global_load_lds(
        (const __attribute__((address_space(1))) void*)g,
        (__attribute__((address_space(3))) void*)l, 16, 0, 0);
}

// fp32 -> bf16 round-to-nearest-even
__device__ __forceinline__ ushort f2bf(float f) {
    union { float f; unsigned u; } v; v.f = f;
    unsigned r = v.u + 0x7fffu + ((v.u >> 16) & 1u);
    return (ushort)(r >> 16);
}
__device__ __forceinline__ unsigned pack_rne(float a, float b) {
    return (unsigned)f2bf(a) | ((unsigned)f2bf(b) << 16);
}
// truncation-pack: low16 = trunc(a), high16 = trunc(b)  (1 VALU op)
__device__ __forceinline__ unsigned pack_trunc(float a, float b) {
    return __builtin_amdgcn_perm(__float_as_uint(a), __float_as_uint(b), 0x03020706u);
}
__device__ __forceinline__ float truncf_bf(float a) {
    return __uint_as_float(__float_as_uint(a) & 0xffff0000u);
}

__global__ __launch_bounds__(256)
void cvt_x(const float* __restrict__ s, ushort* __restrict__ d, float scale) {
    int i = blockIdx.x * 256 + threadIdx.x;
    float4 f = ((const float4*)s)[i];
    ushort4 o;
    o.x = f2bf(f.x * scale); o.y = f2bf(f.y * scale);
    o.z = f2bf(f.z * scale); o.w = f2bf(f.w * scale);
    ((ushort4*)d)[i] = o;
}

// all four 1024x1024 weights in one launch; seg 3 (Wp) gets scale sp
__global__ __launch_bounds__(256)
void cvt_w4(const float* __restrict__ a0, const float* __restrict__ a1,
            const float* __restrict__ a2, const float* __restrict__ a3,
            ushort* __restrict__ d0, ushort* __restrict__ d1,
            ushort* __restrict__ d2, ushort* __restrict__ d3, float sp) {
    const int seg = blockIdx.x >> 10;
    const int i = (blockIdx.x & 1023) * 256 + threadIdx.x;
    const float* s = (seg == 0) ? a0 : (seg == 1) ? a1 : (seg == 2) ? a2 : a3;
    ushort* d = (seg == 0) ? d0 : (seg == 1) ? d1 : (seg == 2) ? d2 : d3;
    const float sc = (seg == 3) ? sp : 1.0f;
    float4 f = ((const float4*)s)[i];
    ushort4 o;
    o.x = f2bf(f.x * sc); o.y = f2bf(f.y * sc);
    o.z = f2bf(f.z * sc); o.w = f2bf(f.w * sc);
    ((ushort4*)d)[i] = o;
}

// ---------------------------------------------------------------------------
// bf16 MFMA GEMM: C = scale * A(MxK) * Bw(NxK)^T. 128x128 tile, BK=32,
// 256 thr = 4 waves (2x2), each wave 4x4 grid of 16x16x32 MFMAs.
// MODE 0: fp32 out row-major. MODE 1: bf16 out [B,H,T,D]. MODE 2: bf16 out
// [B,H,D,T] (V transposed, packed dwordx2 stores).
// ---------------------------------------------------------------------------
template<int MODE>
__global__ __launch_bounds__(256)
void gemm_bf16(const ushort* __restrict__ A, const ushort* __restrict__ Bw,
               void* __restrict__ Cout, int K, int N, float scale)
{
    __shared__ char As[8192];   // addr(m,k) = m*64 + k*2
    __shared__ char Bs[8192];
    const int tid = threadIdx.x;
    const int w = tid >> 6, lane = tid & 63, quad = lane >> 4, l = lane & 15;
    const int n0 = blockIdx.x * 128, m0 = blockIdx.y * 128;
    const int wm = w >> 1, wn = w & 1;

    f32x4 acc[4][4];
#pragma unroll
    for (int i = 0; i < 4; ++i)
#pragma unroll
        for (int j = 0; j < 4; ++j) acc[i][j] = (f32x4){0.f, 0.f, 0.f, 0.f};

    for (int k0 = 0; k0 < K; k0 += 32) {
        __syncthreads();
#pragma unroll
        for (int rr = 0; rr < 2; ++rr) {
            const int rho = w * 2 + rr;
            const int row = rho * 16 + (lane >> 2);
            const int kq  = (lane & 3) * 8;
            glds16(A  + (size_t)(m0 + row) * K + k0 + kq, As + rho * 1024 + lane * 16);
            glds16(Bw + (size_t)(n0 + row) * K + k0 + kq, Bs + rho * 1024 + lane * 16);
        }
        __syncthreads();
        bh8 af[4], bf[4];
#pragma unroll
        for (int mf = 0; mf < 4; ++mf)
            af[mf] = *(const bh8*)(As + (wm * 64 + mf * 16 + l) * 64 + quad * 16);
#pragma unroll
        for (int nf = 0; nf < 4; ++nf)
            bf[nf] = *(const bh8*)(Bs + (wn * 64 + nf * 16 + l) * 64 + quad * 16);
#pragma unroll
        for (int mf = 0; mf < 4; ++mf)
#pragma unroll
            for (int nf = 0; nf < 4; ++nf)
                acc[mf][nf] = __builtin_amdgcn_mfma_f32_16x16x32_bf16(af[mf], bf[nf], acc[mf][nf], 0, 0, 0);
    }

    // epilogue: C/D layout col = l, row = quad*4 + reg
    if (MODE == 1) {
        ushort* dU = (ushort*)Cout;
#pragma unroll
        for (int mf = 0; mf < 4; ++mf)
#pragma unroll
            for (int nf = 0; nf < 4; ++nf) {
                const int mb = m0 + wm * 64 + mf * 16 + quad * 4;
                const int n  = n0 + wn * 64 + nf * 16 + l;
                const int h = n >> 6, dd = n & 63;
#pragma unroll
                for (int reg = 0; reg < 4; ++reg) {
                    const int m = mb + reg;
                    const int b = m >> 11, t = m & (Tn - 1);
                    dU[((size_t)(b * Hn + h) * Tn + t) * Dn + dd] = f2bf(acc[mf][nf][reg] * scale);
                }
            }
    } else if (MODE == 2) {
        ushort* dU = (ushort*)Cout;
#pragma unroll
        for (int mf = 0; mf < 4; ++mf)
#pragma unroll
            for (int nf = 0; nf < 4; ++nf) {
                const int mb = m0 + wm * 64 + mf * 16 + quad * 4;
                const int n  = n0 + wn * 64 + nf * 16 + l;
                const int h = n >> 6, dd = n & 63;
                const int b = mb >> 11, t0 = mb & (Tn - 1);
                uint2 p;
                p.x = pack_rne(acc[mf][nf][0] * scale, acc[mf][nf][1] * scale);
                p.y = pack_rne(acc[mf][nf][2] * scale, acc[mf][nf][3] * scale);
                *(uint2*)(dU + ((size_t)(b * Hn + h) * Dn + dd) * Tn + t0) = p;
            }
    } else {
        float* dF = (float*)Cout;
#pragma unroll
        for (int mf = 0; mf < 4; ++mf)
#pragma unroll
            for (int nf = 0; nf < 4; ++nf) {
                const int mb = m0 + wm * 64 + mf * 16 + quad * 4;
                const int n  = n0 + wn * 64 + nf * 16 + l;
#pragma unroll
                for (int reg = 0; reg < 4; ++reg)
                    dF[(size_t)(mb + reg) * N + n] = acc[mf][nf][reg] * scale;
            }
    }
}

// ---------------------------------------------------------------------------
// MFMA flash attention, S^T formulation.
// Block = (b,h, 128 q-rows), 256 thr = 4 waves; wave w owns 32 q (2 n-tiles).
// S^T = K·Q^T: softmax reduces over keys = over quads (2 shuffles), scalar
// m/l per thread per n-tile. P^T packed to b64 writes (trunc; bias canceled
// by truncated l-sum). V pre-transposed [B,H,D,T], staged with XOR swizzle.
// Ps aliases Ks in two 64-key halves. Output bf16 [B,T,H*D] (O^T regs).
// ---------------------------------------------------------------------------
__global__ __launch_bounds__(256)
void attn_mfma(const ushort* __restrict__ Qg, const ushort* __restrict__ Kg,
               const ushort* __restrict__ Vtg, ushort* __restrict__ Og)
{
    __shared__ char RA[16384];  // K tile (128 keys x 64 d) / Ps (w*4096 slices)
    __shared__ char RB[16384];  // V^T tile (64 d x 128 t), 16-chunk XOR swizzle
    const int tid = threadIdx.x;
    const int w = tid >> 6, lane = tid & 63, quad = lane >> 4, l = lane & 15;
    const int q0 = blockIdx.x * 128;
    const int bh = blockIdx.y, b = bh >> 4, h = bh & 15;
    const ushort* Qp = Qg  + (size_t)bh * Tn * Dn;
    const ushort* Kp = Kg  + (size_t)bh * Tn * Dn;
    const ushort* Vp = Vtg + (size_t)bh * Dn * Tn;   // [d][t]

    // ---- Q frags direct from global (B-operand layout; once per block) ----
    bh8 qf[2][2];
#pragma unroll
    for (int nt = 0; nt < 2; ++nt)
#pragma unroll
        for (int ks = 0; ks < 2; ++ks)
            qf[nt][ks] = *(const bh8*)(Qp + (size_t)(q0 + w * 32 + nt * 16 + l) * Dn + ks * 32 + quad * 8);

    f32x4 oacc[2][4];
    float mrun[2], lrun[2];
#pragma unroll
    for (int nt = 0; nt < 2; ++nt) {
        mrun[nt] = -1e30f; lrun[nt] = 0.f;
#pragma unroll
        for (int dt = 0; dt < 4; ++dt) oacc[nt][dt] = (f32x4){0.f, 0.f, 0.f, 0.f};
    }

    for (int kt = 0; kt < Tn / 128; ++kt) {
        __syncthreads();   // prior iter's Ps/Vt reads drained before restage
        // ---- stage K tile into RA ----
#pragma unroll
        for (int rr = 0; rr < 4; ++rr) {
            const int rho = w * 4 + rr;                    // 0..15
            const int r  = (rho & 7) * 16 + (lane >> 2);   // key row 0..127
            const int dq = (rho >> 3) * 32 + (lane & 3) * 8;
            glds16(Kp + (size_t)(kt * 128 + r) * Dn + dq,
                   RA + (rho >> 3) * 8192 + (rho & 7) * 1024 + lane * 16);
        }
        // ---- stage V^T tile into RB (source-XOR-swizzled) ----
#pragma unroll
        for (int rr = 0; rr < 4; ++rr) {
            const int rho = w * 4 + rr;
            const int d = rho * 4 + (lane >> 4);           // 0..63
            const int csrc = (lane & 15) ^ (d & 15);
            glds16(Vp + (size_t)d * Tn + kt * 128 + csrc * 8, RB + rho * 1024 + lane * 16);
        }
        __syncthreads();

        // ---- S^T = K Q^T : st[nt][kt8], rows=keys(quad*4+reg), col=q(l) ----
        f32x4 st[2][8];
#pragma unroll
        for (int nt = 0; nt < 2; ++nt)
#pragma unroll
            for (int k8 = 0; k8 < 8; ++k8) st[nt][k8] = (f32x4){0.f, 0.f, 0.f, 0.f};
#pragma unroll
        for (int ks = 0; ks < 2; ++ks)
#pragma unroll
            for (int k8 = 0; k8 < 8; ++k8) {
                bh8 kf = *(const bh8*)(RA + ks * 8192 + (k8 * 16 + l) * 64 + quad * 16);
                st[0][k8] = __builtin_amdgcn_mfma_f32_16x16x32_bf16(kf, qf[0][ks], st[0][k8], 0, 0, 0);
                st[1][k8] = __builtin_amdgcn_mfma_f32_16x16x32_bf16(kf, qf[1][ks], st[1][k8], 0, 0, 0);
            }

        // ---- online softmax (column-wise; keys spread over quads) ----
        float al[2];
#pragma unroll
        for (int nt = 0; nt < 2; ++nt) {
            float mx = -1e30f;
#pragma unroll
            for (int k8 = 0; k8 < 8; ++k8)
#pragma unroll
                for (int reg = 0; reg < 4; ++reg) mx = fmaxf(mx, st[nt][k8][reg]);
            mx = fmaxf(mx, __shfl_xor(mx, 16));
            mx = fmaxf(mx, __shfl_xor(mx, 32));
            const float mn = fmaxf(mrun[nt], mx);
            al[nt] = __builtin_amdgcn_exp2f(mrun[nt] - mn);
            mrun[nt] = mn;
            float rs = 0.f;
#pragma unroll
            for (int k8 = 0; k8 < 8; ++k8)
#pragma unroll
                for (int reg = 0; reg < 4; ++reg) {
                    const float e = __builtin_amdgcn_exp2f(st[nt][k8][reg] - mn);
                    st[nt][k8][reg] = e;
                    rs += truncf_bf(e);        // match bf16-trunc P exactly
                }
            rs += __shfl_xor(rs, 16);
            rs += __shfl_xor(rs, 32);
            lrun[nt] = lrun[nt] * al[nt] + rs;
#pragma unroll
            for (int dt = 0; dt < 4; ++dt) oacc[nt][dt] *= al[nt];
        }
        __syncthreads();   // all waves done reading RA as K

        // ---- PV in two 64-key halves; Ps = wave-private 4KB slice of RA ----
        char* Pw = RA + w * 4096;
#pragma unroll
        for (int half = 0; half < 2; ++half) {
#pragma unroll
            for (int nt = 0; nt < 2; ++nt)
#pragma unroll
                for (int k4 = 0; k4 < 4; ++k4) {
                    const int k8 = half * 4 + k4;
                    uint2 p;
                    p.x = pack_trunc(st[nt][k8][0], st[nt][k8][1]);
                    p.y = pack_trunc(st[nt][k8][2], st[nt][k8][3]);
                    const int x = ((k4 * 2 + (quad >> 1)) ^ (l & 7));
                    *(uint2*)(Pw + (nt * 16 + l) * 128 + x * 16 + (quad & 1) * 8) = p;
                }
            __builtin_amdgcn_s_waitcnt(0xC07F);   // lgkmcnt(0): writes visible
#pragma unroll
            for (int cs2 = 0; cs2 < 2; ++cs2) {
                bh8 pf[2];
#pragma unroll
                for (int nt = 0; nt < 2; ++nt)
                    pf[nt] = *(const bh8*)(Pw + (nt * 16 + l) * 128 + ((cs2 * 4 + quad) ^ (l & 7)) * 16);
                const int cg = half * 2 + cs2;
#pragma unroll
                for (int dt = 0; dt < 4; ++dt) {
                    const int d = dt * 16 + l;
                    bh8 vf = *(const bh8*)(RB + d * 256 + (((cg * 4 + quad) ^ (d & 15)) * 16));
                    oacc[0][dt] = __builtin_amdgcn_mfma_f32_16x16x32_bf16(vf, pf[0], oacc[0][dt], 0, 0, 0);
                    oacc[1][dt] = __builtin_amdgcn_mfma_f32_16x16x32_bf16(vf, pf[1], oacc[1][dt], 0, 0, 0);
                }
            }
            if (half == 0) __builtin_amdgcn_s_waitcnt(0xC07F);  // reads done before overwrite
        }
    }

    // ---- epilogue: normalize, write bf16 [B,T,H*D]; O^T: col=q(l), row=d ----
#pragma unroll
    for (int nt = 0; nt < 2; ++nt) {
        const float inv = 1.0f / lrun[nt];
        const int t = q0 + w * 32 + nt * 16 + l;
#pragma unroll
        for (int dt = 0; dt < 4; ++dt) {
            uint2 p;
            p.x = pack_rne(oacc[nt][dt][0] * inv, oacc[nt][dt][1] * inv);
            p.y = pack_rne(oacc[nt][dt][2] * inv, oacc[nt][dt][3] * inv);
            *(uint2*)(Og + ((size_t)(b * Tn + t)) * INNERn + h * 64 + dt * 16 + quad * 4) = p;
        }
    }
}

// ---------------------------------------------------------------------------
extern "C" void kernel_launch(void* const* d_in, const int* in_sizes, int n_in,
                              void* d_out, int out_size, void* d_ws, size_t ws_size,
                              hipStream_t stream)
{
    const float* x  = (const float*)d_in[0];
    const float* Wk = (const float*)d_in[1];
    const float* Wq = (const float*)d_in[2];
    const float* Wv = (const float*)d_in[3];
    const float* Wp = (const float*)d_in[4];
    float* out = (float*)d_out;

    // workspace (all bf16): x | Wk | Wq | Wv | Wp | q | k | vT | ao
    ushort* xb  = (ushort*)d_ws;
    ushort* wkb = xb  + (size_t)Mn * Cn;
    ushort* wqb = wkb + (size_t)INNERn * Cn;
    ushort* wvb = wqb + (size_t)INNERn * Cn;
    ushort* wpb = wvb + (size_t)INNERn * Cn;
    ushort* qw  = wpb + (size_t)OUTn * INNERn;
    ushort* kw  = qw  + (size_t)Mn * INNERn;
    ushort* vtw = kw  + (size_t)Mn * INNERn;   // [B,H,D,T]
    ushort* aow = vtw + (size_t)Mn * INNERn;

    const dim3 blk(256);
    // fold C^-0.5 (=1/32, exact pow2) into x; fold INNER^-0.5 into Wp
    cvt_x<<<dim3(Mn * Cn / 4 / 256), blk, 0, stream>>>(x, xb, 0.03125f);
    cvt_w4<<<dim3(4 * 1024), blk, 0, stream>>>(Wk, Wq, Wv, Wp, wkb, wqb, wvb, wpb, 0.03125f);

    const dim3 gproj(INNERn / 128, Mn / 128);   // 8 x 64
    // q folds d^-0.5 * log2(e) so softmax runs in exp2 domain
    gemm_bf16<1><<<gproj, blk, 0, stream>>>(xb, wqb, qw, Cn, INNERn, 0.125f * 1.44269504f);
    gemm_bf16<1><<<gproj, blk, 0, stream>>>(xb, wkb, kw, Cn, INNERn, 1.0f);
    gemm_bf16<2><<<gproj, blk, 0, stream>>>(xb, wvb, vtw, Cn, INNERn, 1.0f);

    attn_mfma<<<dim3(Tn / 128, Bn * Hn), blk, 0, stream>>>(qw, kw, vtw, aow);

    gemm_bf16<0><<<dim3(OUTn / 128, Mn / 128), blk, 0, stream>>>(aow, wpb, out, INNERn, OUTn, 1.0f);
}

// Round 4
// 287.227 us; speedup vs baseline: 7.0766x; 1.4184x over previous
//
#include <hip/hip_runtime.h>
#include <math.h>

typedef __attribute__((ext_vector_type(8))) short bh8;    // 8 bf16 in 4 VGPRs
typedef __attribute__((ext_vector_type(4))) float f32x4;  // MFMA accumulator

namespace {
constexpr int Bn = 4, Tn = 2048, Cn = 1024, Hn = 16, Dn = 64, INNERn = 1024, OUTn = 1024;
constexpr int Mn = Bn * Tn;  // 8192 tokens
}

// async 16B global->LDS (wave-uniform base + lane*16 placement)
__device__ __forceinline__ void glds16(const void* g, void* l) {
    __builtin_amdgcn_global_load_lds(
        (const __attribute__((address_space(1))) void*)g,
        (__attribute__((address_space(3))) void*)l, 16, 0, 0);
}

// waitcnt vmcnt(0) lgkmcnt(0) (expcnt ignored) + barrier — prefetch-friendly:
// only loads issued at iter top are outstanding, already ~a full body old.
__device__ __forceinline__ void barrier_vm0() {
    __builtin_amdgcn_s_waitcnt(0x0070);
    __builtin_amdgcn_s_barrier();
}

// fp32 -> bf16 round-to-nearest-even
__device__ __forceinline__ ushort f2bf(float f) {
    union { float f; unsigned u; } v; v.f = f;
    unsigned r = v.u + 0x7fffu + ((v.u >> 16) & 1u);
    return (ushort)(r >> 16);
}
__device__ __forceinline__ unsigned pack_rne(float a, float b) {
    return (unsigned)f2bf(a) | ((unsigned)f2bf(b) << 16);
}
// truncation-pack: low16 = trunc(a), high16 = trunc(b)  (1 VALU op)
__device__ __forceinline__ unsigned pack_trunc(float a, float b) {
    return __builtin_amdgcn_perm(__float_as_uint(a), __float_as_uint(b), 0x03020706u);
}

// one launch: x (8192 blocks) + 4 weights (1024 blocks each)
__global__ __launch_bounds__(256)
void cvt_all(const float* __restrict__ x,  const float* __restrict__ Wk,
             const float* __restrict__ Wq, const float* __restrict__ Wv,
             const float* __restrict__ Wp,
             ushort* __restrict__ xb,  ushort* __restrict__ wkb,
             ushort* __restrict__ wqb, ushort* __restrict__ wvb,
             ushort* __restrict__ wpb)
{
    const int bid = blockIdx.x;
    const float* s; ushort* d; float sc; int i;
    if (bid < 8192) {
        s = x; d = xb; sc = 0.03125f;             // fold C^-0.5 (exact pow2)
        i = bid * 256 + threadIdx.x;
    } else {
        const int seg = (bid - 8192) >> 10;
        i = ((bid - 8192) & 1023) * 256 + threadIdx.x;
        s  = (seg == 0) ? Wk : (seg == 1) ? Wq : (seg == 2) ? Wv : Wp;
        d  = (seg == 0) ? wkb : (seg == 1) ? wqb : (seg == 2) ? wvb : wpb;
        sc = (seg == 3) ? 0.03125f : 1.0f;        // fold INNER^-0.5 into Wp
    }
    float4 f = ((const float4*)s)[i];
    ushort4 o;
    o.x = f2bf(f.x * sc); o.y = f2bf(f.y * sc);
    o.z = f2bf(f.z * sc); o.w = f2bf(f.w * sc);
    ((ushort4*)d)[i] = o;
}

// ---------------------------------------------------------------------------
// Fused QKV projection GEMM. C = scale * A(8192x1024) * W(1024x1024)^T for
// W in {Wq,Wk,Wv} selected by blockIdx.x>>3. 128x128 tile, BK=32, dbuf LDS
// with single waitcnt(vm0)+barrier per K-iter (prefetch stays in flight).
// Q/K epilogue: bf16 [B,H,T,D]; V epilogue: bf16 [B,H,D,T] (transposed).
// ---------------------------------------------------------------------------
__global__ __launch_bounds__(256)
void gemm_qkv(const ushort* __restrict__ A, const ushort* __restrict__ Wq,
              const ushort* __restrict__ Wk, const ushort* __restrict__ Wv,
              ushort* __restrict__ Oq, ushort* __restrict__ Ok,
              ushort* __restrict__ Ovt, float qscale)
{
    __shared__ char As[2][8192];   // addr(m,k) = m*64 + k*2
    __shared__ char Bs[2][8192];
    const int tid = threadIdx.x;
    const int w = tid >> 6, lane = tid & 63, quad = lane >> 4, l = lane & 15;
    const int sel = blockIdx.x >> 3;
    const ushort* Bw = (sel == 0) ? Wq : (sel == 1) ? Wk : Wv;
    const int n0 = (blockIdx.x & 7) * 128, m0 = blockIdx.y * 128;
    const int wm = w >> 1, wn = w & 1;

    auto stage = [&](int bsel, int k0) {
#pragma unroll
        for (int rr = 0; rr < 2; ++rr) {
            const int rho = w * 2 + rr;
            const int row = rho * 16 + (lane >> 2);
            const int kq  = (lane & 3) * 8;
            glds16(A  + (size_t)(m0 + row) * Cn + k0 + kq, As[bsel] + rho * 1024 + lane * 16);
            glds16(Bw + (size_t)(n0 + row) * Cn + k0 + kq, Bs[bsel] + rho * 1024 + lane * 16);
        }
    };

    f32x4 acc[4][4];
#pragma unroll
    for (int i = 0; i < 4; ++i)
#pragma unroll
        for (int j = 0; j < 4; ++j) acc[i][j] = (f32x4){0.f, 0.f, 0.f, 0.f};

    stage(0, 0);
    barrier_vm0();
#pragma unroll 2
    for (int it = 0; it < 32; ++it) {
        const int cur = it & 1;
        if (it < 31) stage(cur ^ 1, (it + 1) * 32);
        const char* Ac = As[cur]; const char* Bc = Bs[cur];
        bh8 af[4], bf[4];
#pragma unroll
        for (int mf = 0; mf < 4; ++mf)
            af[mf] = *(const bh8*)(Ac + (wm * 64 + mf * 16 + l) * 64 + quad * 16);
#pragma unroll
        for (int nf = 0; nf < 4; ++nf)
            bf[nf] = *(const bh8*)(Bc + (wn * 64 + nf * 16 + l) * 64 + quad * 16);
#pragma unroll
        for (int mf = 0; mf < 4; ++mf)
#pragma unroll
            for (int nf = 0; nf < 4; ++nf)
                acc[mf][nf] = __builtin_amdgcn_mfma_f32_16x16x32_bf16(af[mf], bf[nf], acc[mf][nf], 0, 0, 0);
        barrier_vm0();
    }

    // epilogue: C/D layout col = l, row = quad*4 + reg
    if (sel < 2) {
        ushort* dU = (sel == 0) ? Oq : Ok;
        const float scale = (sel == 0) ? qscale : 1.0f;
#pragma unroll
        for (int mf = 0; mf < 4; ++mf)
#pragma unroll
            for (int nf = 0; nf < 4; ++nf) {
                const int mb = m0 + wm * 64 + mf * 16 + quad * 4;
                const int n  = n0 + wn * 64 + nf * 16 + l;
                const int h = n >> 6, dd = n & 63;
#pragma unroll
                for (int reg = 0; reg < 4; ++reg) {
                    const int m = mb + reg;
                    const int b = m >> 11, t = m & (Tn - 1);
                    dU[((size_t)(b * Hn + h) * Tn + t) * Dn + dd] = f2bf(acc[mf][nf][reg]* scale);
                }
            }
    } else {
#pragma unroll
        for (int mf = 0; mf < 4; ++mf)
#pragma unroll
            for (int nf = 0; nf < 4; ++nf) {
                const int mb = m0 + wm * 64 + mf * 16 + quad * 4;
                const int n  = n0 + wn * 64 + nf * 16 + l;
                const int h = n >> 6, dd = n & 63;
                const int b = mb >> 11, t0 = mb & (Tn - 1);
                uint2 p;
                p.x = pack_rne(acc[mf][nf][0], acc[mf][nf][1]);
                p.y = pack_rne(acc[mf][nf][2], acc[mf][nf][3]);
                *(uint2*)(Ovt + ((size_t)(b * Hn + h) * Dn + dd) * Tn + t0) = p;
            }
    }
}

// ---------------------------------------------------------------------------
// Output projection: out = ao(8192x1024) * Wp(1024x1024)^T, fp32 out.
// Same dbuf structure.
// ---------------------------------------------------------------------------
__global__ __launch_bounds__(256)
void gemm_po(const ushort* __restrict__ A, const ushort* __restrict__ Bw,
             float* __restrict__ Cout)
{
    __shared__ char As[2][8192];
    __shared__ char Bs[2][8192];
    const int tid = threadIdx.x;
    const int w = tid >> 6, lane = tid & 63, quad = lane >> 4, l = lane & 15;
    const int n0 = blockIdx.x * 128, m0 = blockIdx.y * 128;
    const int wm = w >> 1, wn = w & 1;

    auto stage = [&](int bsel, int k0) {
#pragma unroll
        for (int rr = 0; rr < 2; ++rr) {
            const int rho = w * 2 + rr;
            const int row = rho * 16 + (lane >> 2);
            const int kq  = (lane & 3) * 8;
            glds16(A  + (size_t)(m0 + row) * Cn + k0 + kq, As[bsel] + rho * 1024 + lane * 16);
            glds16(Bw + (size_t)(n0 + row) * Cn + k0 + kq, Bs[bsel] + rho * 1024 + lane * 16);
        }
    };

    f32x4 acc[4][4];
#pragma unroll
    for (int i = 0; i < 4; ++i)
#pragma unroll
        for (int j = 0; j < 4; ++j) acc[i][j] = (f32x4){0.f, 0.f, 0.f, 0.f};

    stage(0, 0);
    barrier_vm0();
#pragma unroll 2
    for (int it = 0; it < 32; ++it) {
        const int cur = it & 1;
        if (it < 31) stage(cur ^ 1, (it + 1) * 32);
        const char* Ac = As[cur]; const char* Bc = Bs[cur];
        bh8 af[4], bf[4];
#pragma unroll
        for (int mf = 0; mf < 4; ++mf)
            af[mf] = *(const bh8*)(Ac + (wm * 64 + mf * 16 + l) * 64 + quad * 16);
#pragma unroll
        for (int nf = 0; nf < 4; ++nf)
            bf[nf] = *(const bh8*)(Bc + (wn * 64 + nf * 16 + l) * 64 + quad * 16);
#pragma unroll
        for (int mf = 0; mf < 4; ++mf)
#pragma unroll
            for (int nf = 0; nf < 4; ++nf)
                acc[mf][nf] = __builtin_amdgcn_mfma_f32_16x16x32_bf16(af[mf], bf[nf], acc[mf][nf], 0, 0, 0);
        barrier_vm0();
    }

#pragma unroll
    for (int mf = 0; mf < 4; ++mf)
#pragma unroll
        for (int nf = 0; nf < 4; ++nf) {
            const int mb = m0 + wm * 64 + mf * 16 + quad * 4;
            const int n  = n0 + wn * 64 + nf * 16 + l;
#pragma unroll
            for (int reg = 0; reg < 4; ++reg)
                Cout[(size_t)(mb + reg) * OUTn + n] = acc[mf][nf][reg];
        }
}

// ---------------------------------------------------------------------------
// MFMA flash attention, S^T formulation, streaming softmax (no running max:
// scores are bounded, softmax is shift-invariant; exp2 domain, log2e folded
// into q upstream). l computed by ones-MFMA over the SAME truncated bf16 P
// used for PV (numerator/denominator consistent). 64-key tiles, K/V double-
// buffered via glds prefetch + single waitcnt(vm0)/barrier per iter.
// Block = (b,h, 128 q), 4 waves x 32 q. LDS 48KB -> 3 blocks/CU.
// ---------------------------------------------------------------------------
__global__ __launch_bounds__(256, 3)
void attn_mfma(const ushort* __restrict__ Qg, const ushort* __restrict__ Kg,
               const ushort* __restrict__ Vtg, ushort* __restrict__ Og)
{
    __shared__ char KT[2][8192];  // (r,d): r*64 + (d&31)*2, halves ks at +4096
    __shared__ char VT[2][8192];  // (c,d): d*128 + ((c>>3)^(d&7))*16 + (c&7)*2
    __shared__ char PS[16384];    // per-wave 4KB: row q(nt*16+l)*128, chunks XOR (q&7)

    const int tid = threadIdx.x;
    const int w = tid >> 6, lane = tid & 63, quad = lane >> 4, l = lane & 15;
    const int q0 = blockIdx.x * 128;
    const int bh = blockIdx.y, b = bh >> 4, h = bh & 15;
    const ushort* Qp = Qg  + (size_t)bh * Tn * Dn;
    const ushort* Kp = Kg  + (size_t)bh * Tn * Dn;
    const ushort* Vp = Vtg + (size_t)bh * Dn * Tn;   // [d][t]

    auto stageK = [&](char* buf, int kt) {
#pragma unroll
        for (int rr = 0; rr < 2; ++rr) {
            const int rho = w * 2 + rr;                    // 0..7
            const int r  = (rho & 3) * 16 + (lane >> 2);   // key row 0..63
            const int dq = (rho >> 2) * 32 + (lane & 3) * 8;
            glds16(Kp + (size_t)(kt * 64 + r) * Dn + dq, buf + rho * 1024 + lane * 16);
        }
    };
    auto stageV = [&](char* buf, int kt) {
#pragma unroll
        for (int rr = 0; rr < 2; ++rr) {
            const int rho = w * 2 + rr;
            const int d = rho * 8 + (lane >> 3);           // 0..63
            const int csrc = (lane & 7) ^ ((lane >> 3) & 7);
            glds16(Vp + (size_t)d * Tn + kt * 64 + csrc * 8, buf + rho * 1024 + lane * 16);
        }
    };

    // ---- Q frags direct from global (B-operand layout; once per block) ----
    bh8 qf[2][2];
#pragma unroll
    for (int nt = 0; nt < 2; ++nt)
#pragma unroll
        for (int ks = 0; ks < 2; ++ks)
            qf[nt][ks] = *(const bh8*)(Qp + (size_t)(q0 + w * 32 + nt * 16 + l) * Dn + ks * 32 + quad * 8);

    bh8 ones;
#pragma unroll
    for (int i = 0; i < 8; ++i) ones[i] = (short)0x3F80;   // bf16 1.0

    f32x4 oacc[2][4], lacc[2];
#pragma unroll
    for (int nt = 0; nt < 2; ++nt) {
        lacc[nt] = (f32x4){0.f, 0.f, 0.f, 0.f};
#pragma unroll
        for (int dt = 0; dt < 4; ++dt) oacc[nt][dt] = (f32x4){0.f, 0.f, 0.f, 0.f};
    }

    char* Pw = PS + w * 4096;
    const f32x4 zero = (f32x4){0.f, 0.f, 0.f, 0.f};

    stageK(KT[0], 0);
    stageV(VT[0], 0);
    barrier_vm0();

#pragma unroll 2
    for (int kt = 0; kt < Tn / 64; ++kt) {
        const int cur = kt & 1;
        if (kt < Tn / 64 - 1) {           // prefetch next tile (in flight all body)
            stageK(KT[cur ^ 1], kt + 1);
            stageV(VT[cur ^ 1], kt + 1);
        }
        const char* Kc = KT[cur];
        const char* Vc = VT[cur];

        // ---- S^T = K Q^T : rows=keys(quad*4+reg), col=q(l) ----
        f32x4 st[2][4];
#pragma unroll
        for (int k8 = 0; k8 < 4; ++k8) {
            bh8 kf = *(const bh8*)(Kc + (k8 * 16 + l) * 64 + quad * 16);
            st[0][k8] = __builtin_amdgcn_mfma_f32_16x16x32_bf16(kf, qf[0][0], zero, 0, 0, 0);
            st[1][k8] = __builtin_amdgcn_mfma_f32_16x16x32_bf16(kf, qf[1][0], zero, 0, 0, 0);
        }
#pragma unroll
        for (int k8 = 0; k8 < 4; ++k8) {
            bh8 kf = *(const bh8*)(Kc + 4096 + (k8 * 16 + l) * 64 + quad * 16);
            st[0][k8] = __builtin_amdgcn_mfma_f32_16x16x32_bf16(kf, qf[0][1], st[0][k8], 0, 0, 0);
            st[1][k8] = __builtin_amdgcn_mfma_f32_16x16x32_bf16(kf, qf[1][1], st[1][k8], 0, 0, 0);
        }

        // ---- P = exp2(S), truncated to bf16, straight into Ps ----
#pragma unroll
        for (int nt = 0; nt < 2; ++nt)
#pragma unroll
            for (int k8 = 0; k8 < 4; ++k8) {
                const float e0 = __builtin_amdgcn_exp2f(st[nt][k8][0]);
                const float e1 = __builtin_amdgcn_exp2f(st[nt][k8][1]);
                const float e2 = __builtin_amdgcn_exp2f(st[nt][k8][2]);
                const float e3 = __builtin_amdgcn_exp2f(st[nt][k8][3]);
                uint2 p;
                p.x = pack_trunc(e0, e1);
                p.y = pack_trunc(e2, e3);
                const int x = (k8 * 2 + (quad >> 1)) ^ (l & 7);
                *(uint2*)(Pw + (nt * 16 + l) * 128 + x * 16 + (quad & 1) * 8) = p;
            }
        __builtin_amdgcn_s_waitcnt(0xC07F);  // lgkmcnt(0): wave-private Ps visible

        // ---- O += P V ; l += ones*P (same bf16 P -> consistent softmax) ----
#pragma unroll
        for (int cg = 0; cg < 2; ++cg) {
            const int xc = ((cg * 4 + quad) ^ (l & 7)) * 16;
            bh8 pf0 = *(const bh8*)(Pw + (0 * 16 + l) * 128 + xc);
            bh8 pf1 = *(const bh8*)(Pw + (1 * 16 + l) * 128 + xc);
            lacc[0] = __builtin_amdgcn_mfma_f32_16x16x32_bf16(ones, pf0, lacc[0], 0, 0, 0);
            lacc[1] = __builtin_amdgcn_mfma_f32_16x16x32_bf16(ones, pf1, lacc[1], 0, 0, 0);
#pragma unroll
            for (int dt = 0; dt < 4; ++dt) {
                bh8 vf = *(const bh8*)(Vc + (dt * 16 + l) * 128 + xc);
                oacc[0][dt] = __builtin_amdgcn_mfma_f32_16x16x32_bf16(vf, pf0, oacc[0][dt], 0, 0, 0);
                oacc[1][dt] = __builtin_amdgcn_mfma_f32_16x16x32_bf16(vf, pf1, oacc[1][dt], 0, 0, 0);
            }
        }
        barrier_vm0();   // prefetch loads (issued at top) drained; all reads done
    }

    // ---- epilogue: normalize, write bf16 [B,T,H*D]; O^T: col=q(l), row=d ----
#pragma unroll
    for (int nt = 0; nt < 2; ++nt) {
        const float inv = 1.0f / lacc[nt][0];
        const int t = q0 + w * 32 + nt * 16 + l;
#pragma unroll
        for (int dt = 0; dt < 4; ++dt) {
            uint2 p;
            p.x = pack_rne(oacc[nt][dt][0] * inv, oacc[nt][dt][1] * inv);
            p.y = pack_rne(oacc[nt][dt][2] * inv, oacc[nt][dt][3] * inv);
            *(uint2*)(Og + ((size_t)(b * Tn + t)) * INNERn + h * 64 + dt * 16 + quad * 4) = p;
        }
    }
}

// ---------------------------------------------------------------------------
extern "C" void kernel_launch(void* const* d_in, const int* in_sizes, int n_in,
                              void* d_out, int out_size, void* d_ws, size_t ws_size,
                              hipStream_t stream)
{
    const float* x  = (const float*)d_in[0];
    const float* Wk = (const float*)d_in[1];
    const float* Wq = (const float*)d_in[2];
    const float* Wv = (const float*)d_in[3];
    const float* Wp = (const float*)d_in[4];
    float* out = (float*)d_out;

    // workspace (all bf16): x | Wk | Wq | Wv | Wp | q | k | vT | ao
    ushort* xb  = (ushort*)d_ws;
    ushort* wkb = xb  + (size_t)Mn * Cn;
    ushort* wqb = wkb + (size_t)INNERn * Cn;
    ushort* wvb = wqb + (size_t)INNERn * Cn;
    ushort* wpb = wvb + (size_t)INNERn * Cn;
    ushort* qw  = wpb + (size_t)OUTn * INNERn;
    ushort* kw  = qw  + (size_t)Mn * INNERn;
    ushort* vtw = kw  + (size_t)Mn * INNERn;   // [B,H,D,T]
    ushort* aow = vtw + (size_t)Mn * INNERn;

    const dim3 blk(256);
    cvt_all<<<dim3(8192 + 4096), blk, 0, stream>>>(x, Wk, Wq, Wv, Wp,
                                                   xb, wkb, wqb, wvb, wpb);

    // q folds d^-0.5 * log2(e) so softmax runs in exp2 domain
    gemm_qkv<<<dim3(3 * 8, Mn / 128), blk, 0, stream>>>(xb, wqb, wkb, wvb,
                                                        qw, kw, vtw, 0.125f * 1.44269504f);

    attn_mfma<<<dim3(Tn / 128, Bn * Hn), blk, 0, stream>>>(qw, kw, vtw, aow);

    gemm_po<<<dim3(OUTn / 128, Mn / 128), blk, 0, stream>>>(aow, wpb, out);
}